// Round 2
// baseline (322.283 us; speedup 1.0000x reference)
//
#include <hip/hip_runtime.h>
#include <hip/hip_bf16.h>
#include <stdint.h>

#define SEQ 4096
#define BATCH 16
#define HID 512
#define ATT_OFF (BATCH * HID)                 // 8192  elements into d_out
#define NSS_OFF (BATCH * HID + BATCH * SEQ)   // 73728 elements into d_out

typedef unsigned short u16;
typedef unsigned int u32;

__device__ __forceinline__ float bflo(u32 w) { return __uint_as_float(w << 16); }
__device__ __forceinline__ float bfhi(u32 w) { return __uint_as_float(w & 0xffff0000u); }

__device__ __forceinline__ u16 f2bf(float f) {  // round-to-nearest-even
  u32 u = __float_as_uint(f);
  return (u16)((u + 0x7fffu + ((u >> 16) & 1u)) >> 16);
}

// Runtime dtype probe: tss values lie in [0.5, 1.5) (strictly positive).
// As bf16, every u16 is in [0x3F00, 0x3FC0]. As fp32, even-indexed u16s are
// random low-mantissa bits (P(all 4 in window) ~ 7e-11). Wave-uniform branch.
__device__ __forceinline__ int probe_bf16(const void* tssp) {
  const u16* t = (const u16*)tssp;
  int ok = 1;
  #pragma unroll
  for (int i = 0; i < 8; i += 2) {
    u16 u = t[i];
    ok &= (u >= 0x3F00 && u <= 0x3FC0) ? 1 : 0;
  }
  return ok;
}

template <int BF>
__device__ __forceinline__ float ld1(const void* p, size_t i) {
  if (BF) return __uint_as_float(((u32)((const u16*)p)[i]) << 16);
  return ((const float*)p)[i];
}

template <int BF>
__device__ __forceinline__ void st1(void* p, size_t i, float v) {
  if (BF) ((u16*)p)[i] = f2bf(v);
  else    ((float*)p)[i] = v;
}

template <int BF>
__device__ __forceinline__ void load8(const void* p, size_t e, float* o) {
  if (BF) {
    uint4 v = *(const uint4*)((const u16*)p + e);
    o[0]=bflo(v.x); o[1]=bfhi(v.x); o[2]=bflo(v.y); o[3]=bfhi(v.y);
    o[4]=bflo(v.z); o[5]=bfhi(v.z); o[6]=bflo(v.w); o[7]=bfhi(v.w);
  } else {
    const float4* f = (const float4*)((const float*)p + e);
    float4 a = f[0], b = f[1];
    o[0]=a.x; o[1]=a.y; o[2]=a.z; o[3]=a.w;
    o[4]=b.x; o[5]=b.y; o[6]=b.z; o[7]=b.w;
  }
}

__device__ __forceinline__ float fast_tanh(float x) {
  float e = __expf(2.0f * x);
  return 1.0f - 2.0f * __builtin_amdgcn_rcpf(e + 1.0f);
}

__device__ __forceinline__ float wave_sum(float acc) {
  #pragma unroll
  for (int off = 32; off; off >>= 1) acc += __shfl_xor(acc, off, 64);
  return acc;
}

// ---------- K1 ----------
template <int BF>
__device__ __forceinline__ void k_dec_body(
    const void* oh, const void* W, const void* bias, float* dec) {
  int tid = threadIdx.x;
  int gw = blockIdx.x * 4 + (tid >> 6);
  int lane = tid & 63;
  int k = gw & (HID - 1);
  int b = gw >> 9;
  float wv[8], ov[8];
  load8<BF>(W,  (size_t)k * HID + lane * 8, wv);
  load8<BF>(oh, (size_t)b * HID + lane * 8, ov);
  float acc = 0.0f;
  #pragma unroll
  for (int j = 0; j < 8; ++j) acc += wv[j] * ov[j];
  acc = wave_sum(acc);
  if (lane == 0) dec[b * HID + k] = acc + ld1<BF>(bias, k);
}

__global__ __launch_bounds__(256) void k_dec(
    const void* oh, const void* W, const void* bias, const void* tss,
    float* dec, float* denom) {
  if (blockIdx.x == 0 && threadIdx.x < BATCH) denom[threadIdx.x] = 0.0f;
  if (probe_bf16(tss)) k_dec_body<1>(oh, W, bias, dec);
  else                 k_dec_body<0>(oh, W, bias, dec);
}

// ---------- K2 ----------
template <int BF>
__device__ __forceinline__ void k_scores_body(
    const void* ef, const void* maskp, const void* tssp, const void* vp,
    const float* dec, float* w_out, float* denom, void* out) {
  int tid = threadIdx.x, lane = tid & 63, wave = tid >> 6;
  int blk = blockIdx.x;
  int b = blk >> 8;
  int s_base = (blk & 255) * 16;
  float dv[8], vv[8];
  #pragma unroll
  for (int j = 0; j < 8; ++j) dv[j] = dec[b * HID + lane * 8 + j];
  load8<BF>(vp, lane * 8, vv);
  __shared__ float wpart[16];
  #pragma unroll
  for (int i = 0; i < 4; ++i) {
    int s = s_base + wave * 4 + i;
    float ev[8];
    load8<BF>(ef, ((size_t)s * BATCH + b) * HID + lane * 8, ev);
    float acc = 0.0f;
    #pragma unroll
    for (int j = 0; j < 8; ++j) acc += fast_tanh(ev[j] + dv[j]) * vv[j];
    acc = wave_sum(acc);
    if (lane == 0) {
      float p  = __expf(acc);
      float ts = ld1<BF>(tssp,  b * SEQ + s);
      float m  = ld1<BF>(maskp, b * SEQ + s);
      float w  = p * m * __builtin_amdgcn_rcpf(ts);
      st1<BF>(out, NSS_OFF + b * SEQ + s, p + ts);
      w_out[b * SEQ + s] = w;
      wpart[wave * 4 + i] = w;
    }
  }
  __syncthreads();
  if (tid == 0) {
    float sum = 0.0f;
    #pragma unroll
    for (int j = 0; j < 16; ++j) sum += wpart[j];
    atomicAdd(&denom[b], sum);
  }
}

__global__ __launch_bounds__(256) void k_scores(
    const void* ef, const void* maskp, const void* tssp, const void* vp,
    const float* dec, float* w_out, float* denom, void* out) {
  if (probe_bf16(tssp)) k_scores_body<1>(ef, maskp, tssp, vp, dec, w_out, denom, out);
  else                  k_scores_body<0>(ef, maskp, tssp, vp, dec, w_out, denom, out);
}

// ---------- K3 ----------
#define K3_CHUNK 128
template <int BF>
__device__ __forceinline__ void k_context_body(
    const void* eo, const float* w, const float* denom,
    float* partial, void* out) {
  int blk = blockIdx.x;
  int b = blk >> 5;
  int chunk = blk & 31;
  int s0 = chunk * K3_CHUNK;
  int tid = threadIdx.x, lane = tid & 63, sg = tid >> 6;
  __shared__ float w_s[K3_CHUNK];
  __shared__ float red[192 * 8];
  float inv_d = __builtin_amdgcn_rcpf(denom[b]);
  if (tid < K3_CHUNK) {
    float wv = w[b * SEQ + s0 + tid];
    w_s[tid] = wv;
    st1<BF>(out, ATT_OFF + b * SEQ + s0 + tid, wv * inv_d);
  }
  __syncthreads();
  float a[8] = {0,0,0,0,0,0,0,0};
  #pragma unroll 4
  for (int i = 0; i < K3_CHUNK / 4; ++i) {
    int sl = 4 * i + sg;
    int s = s0 + sl;
    float ev[8];
    load8<BF>(eo, ((size_t)s * BATCH + b) * HID + lane * 8, ev);
    float ws = w_s[sl];
    #pragma unroll
    for (int j = 0; j < 8; ++j) a[j] += ws * ev[j];
  }
  if (sg > 0) {
    float* r = &red[(((sg - 1) * 64) + lane) * 8];
    #pragma unroll
    for (int j = 0; j < 8; ++j) r[j] = a[j];
  }
  __syncthreads();
  if (sg == 0) {
    #pragma unroll
    for (int k = 0; k < 3; ++k) {
      const float* r = &red[((k * 64) + lane) * 8];
      #pragma unroll
      for (int j = 0; j < 8; ++j) a[j] += r[j];
    }
    float4* p4 = (float4*)(partial + (size_t)chunk * (BATCH * HID) + b * HID + lane * 8);
    p4[0] = make_float4(a[0], a[1], a[2], a[3]);
    p4[1] = make_float4(a[4], a[5], a[6], a[7]);
  }
}

__global__ __launch_bounds__(256) void k_context(
    const void* eo, const float* w, const float* denom, const void* tssp,
    float* partial, void* out) {
  if (probe_bf16(tssp)) k_context_body<1>(eo, w, denom, partial, out);
  else                  k_context_body<0>(eo, w, denom, partial, out);
}

// ---------- K4 ----------
__global__ __launch_bounds__(256) void k_reduce_ctx(
    const float* __restrict__ partial, const float* __restrict__ denom,
    const void* tssp, void* out) {
  int idx = blockIdx.x * 256 + threadIdx.x;
  int b = idx >> 9;
  float sum = 0.0f;
  #pragma unroll
  for (int c = 0; c < 32; ++c) sum += partial[c * (BATCH * HID) + idx];
  float v = sum * __builtin_amdgcn_rcpf(denom[b]);
  if (probe_bf16(tssp)) st1<1>(out, idx, v);
  else                  st1<0>(out, idx, v);
}

extern "C" void kernel_launch(void* const* d_in, const int* in_sizes, int n_in,
                              void* d_out, int out_size, void* d_ws, size_t ws_size,
                              hipStream_t stream) {
  const void* oh   = d_in[0];
  const void* eo   = d_in[1];
  const void* ef   = d_in[2];
  const void* mask = d_in[3];
  const void* tss  = d_in[4];
  const void* W    = d_in[5];
  const void* bias = d_in[6];
  const void* v    = d_in[7];

  float* ws      = (float*)d_ws;
  float* dec     = ws;                    // 8192
  float* w_buf   = dec + BATCH * HID;     // 65536
  float* denom   = w_buf + BATCH * SEQ;   // 16
  float* partial = denom + 16;            // 262144  (total ~1.35 MB)

  k_dec       <<<2048, 256, 0, stream>>>(oh, W, bias, tss, dec, denom);
  k_scores    <<<4096, 256, 0, stream>>>(ef, mask, tss, v, dec, w_buf, denom, d_out);
  k_context   <<< 512, 256, 0, stream>>>(eo, w_buf, denom, tss, partial, d_out);
  k_reduce_ctx<<<  32, 256, 0, stream>>>(partial, denom, tss, d_out);
}

// Round 3
// 308.221 us; speedup vs baseline: 1.0456x; 1.0456x over previous
//
#include <hip/hip_runtime.h>
#include <hip/hip_bf16.h>
#include <stdint.h>

#define SEQ 4096
#define BATCH 16
#define HID 512
#define ATT_OFF (BATCH * HID)                 // 8192  elements into d_out
#define NSS_OFF (BATCH * HID + BATCH * SEQ)   // 73728 elements into d_out
#define SPB 64                                // s per block in fused kernel
#define NCHUNK (SEQ / SPB)                    // 64 chunks per batch
#define SPW (SPB / 4)                         // 16 s per wave

typedef unsigned short u16;
typedef unsigned int u32;

__device__ __forceinline__ float bflo(u32 w) { return __uint_as_float(w << 16); }
__device__ __forceinline__ float bfhi(u32 w) { return __uint_as_float(w & 0xffff0000u); }

__device__ __forceinline__ u16 f2bf(float f) {  // round-to-nearest-even
  u32 u = __float_as_uint(f);
  return (u16)((u + 0x7fffu + ((u >> 16) & 1u)) >> 16);
}

// Runtime dtype probe (kept as insurance; R1-NaN vs R2-pass proves fp32).
// tss in [0.5,1.5): bf16 u16 in [0x3F00,0x3FC0]; fp32 low-u16s are random.
__device__ __forceinline__ int probe_bf16(const void* tssp) {
  const u16* t = (const u16*)tssp;
  int ok = 1;
  #pragma unroll
  for (int i = 0; i < 8; i += 2) {
    u16 u = t[i];
    ok &= (u >= 0x3F00 && u <= 0x3FC0) ? 1 : 0;
  }
  return ok;
}

template <int BF>
__device__ __forceinline__ float ld1(const void* p, size_t i) {
  if (BF) return __uint_as_float(((u32)((const u16*)p)[i]) << 16);
  return ((const float*)p)[i];
}

template <int BF>
__device__ __forceinline__ void st1(void* p, size_t i, float v) {
  if (BF) ((u16*)p)[i] = f2bf(v);
  else    ((float*)p)[i] = v;
}

template <int BF>
__device__ __forceinline__ void load8(const void* p, size_t e, float* o) {
  if (BF) {
    uint4 v = *(const uint4*)((const u16*)p + e);
    o[0]=bflo(v.x); o[1]=bfhi(v.x); o[2]=bflo(v.y); o[3]=bfhi(v.y);
    o[4]=bflo(v.z); o[5]=bfhi(v.z); o[6]=bflo(v.w); o[7]=bfhi(v.w);
  } else {
    const float4* f = (const float4*)((const float*)p + e);
    float4 a = f[0], b = f[1];
    o[0]=a.x; o[1]=a.y; o[2]=a.z; o[3]=a.w;
    o[4]=b.x; o[5]=b.y; o[6]=b.z; o[7]=b.w;
  }
}

__device__ __forceinline__ float fast_tanh(float x) {
  float e = __expf(2.0f * x);
  return 1.0f - 2.0f * __builtin_amdgcn_rcpf(e + 1.0f);
}

// Butterfly: leaves the full sum in ALL 64 lanes.
__device__ __forceinline__ float wave_sum(float acc) {
  #pragma unroll
  for (int off = 32; off; off >>= 1) acc += __shfl_xor(acc, off, 64);
  return acc;
}

// ---------- K1: dec[b,k] = sum_h oh[b,h]*W[k,h] + bias[k] ----------
template <int BF>
__device__ __forceinline__ void k_dec_body(
    const void* oh, const void* W, const void* bias, float* dec) {
  int tid = threadIdx.x;
  int gw = blockIdx.x * 4 + (tid >> 6);   // 8192 waves = 16 b * 512 k
  int lane = tid & 63;
  int k = gw & (HID - 1);
  int b = gw >> 9;
  float wv[8], ov[8];
  load8<BF>(W,  (size_t)k * HID + lane * 8, wv);
  load8<BF>(oh, (size_t)b * HID + lane * 8, ov);
  float acc = 0.0f;
  #pragma unroll
  for (int j = 0; j < 8; ++j) acc += wv[j] * ov[j];
  acc = wave_sum(acc);
  if (lane == 0) dec[b * HID + k] = acc + ld1<BF>(bias, k);
}

__global__ __launch_bounds__(256) void k_dec(
    const void* oh, const void* W, const void* bias, const void* tss,
    float* dec, float* denom) {
  if (blockIdx.x == 0 && threadIdx.x < BATCH) denom[threadIdx.x] = 0.0f;
  if (probe_bf16(tss)) k_dec_body<1>(oh, W, bias, dec);
  else                 k_dec_body<0>(oh, W, bias, dec);
}

// ---------- K2: fused scores + context-partial; streams ef AND eo ----------
// 1024 blocks = 16 b * 64 chunks of 64 s. Each wave owns 16 consecutive s:
// per s: score -> w (in all lanes, via butterfly), nss/w writes, then
// immediately a[] += w * eo[s]. Cross-wave reduce -> partial[b][chunk][h].
template <int BF>
__device__ __forceinline__ void k_fused_body(
    const void* ef, const void* eo, const void* maskp, const void* tssp,
    const void* vp, const float* dec, float* w_buf, float* denom,
    float* partial, void* out) {
  int tid = threadIdx.x, lane = tid & 63, wave = tid >> 6;
  int blk = blockIdx.x;
  int b = blk >> 6;
  int chunk = blk & (NCHUNK - 1);
  int s0 = chunk * SPB + wave * SPW;
  float dv[8], vv[8];
  #pragma unroll
  for (int j = 0; j < 8; ++j) dv[j] = dec[b * HID + lane * 8 + j];
  load8<BF>(vp, lane * 8, vv);
  float a[8] = {0,0,0,0,0,0,0,0};
  float wsum = 0.0f;
  for (int i = 0; i < SPW; ++i) {
    int s = s0 + i;
    size_t rowoff = ((size_t)s * BATCH + b) * HID + lane * 8;
    float ev[8];
    load8<BF>(ef, rowoff, ev);
    float eov[8];
    load8<BF>(eo, rowoff, eov);   // independent of score math -> overlaps
    float acc = 0.0f;
    #pragma unroll
    for (int j = 0; j < 8; ++j) acc += fast_tanh(ev[j] + dv[j]) * vv[j];
    acc = wave_sum(acc);          // full sum in all lanes
    float p  = __expf(acc);
    float ts = ld1<BF>(tssp,  b * SEQ + s);   // same addr all lanes: broadcast
    float m  = ld1<BF>(maskp, b * SEQ + s);
    float w  = p * m * __builtin_amdgcn_rcpf(ts);
    if (lane == 0) {
      st1<BF>(out, NSS_OFF + b * SEQ + s, p + ts);
      w_buf[b * SEQ + s] = w;
      wsum += w;
    }
    #pragma unroll
    for (int j = 0; j < 8; ++j) a[j] += w * eov[j];
  }
  __shared__ float red[3 * 64 * 8];
  __shared__ float wpart[4];
  if (lane == 0) wpart[wave] = wsum;
  if (wave > 0) {
    float* r = &red[(((wave - 1) * 64) + lane) * 8];
    #pragma unroll
    for (int j = 0; j < 8; ++j) r[j] = a[j];
  }
  __syncthreads();
  if (wave == 0) {
    #pragma unroll
    for (int k = 0; k < 3; ++k) {
      const float* r = &red[((k * 64) + lane) * 8];
      #pragma unroll
      for (int j = 0; j < 8; ++j) a[j] += r[j];
    }
    float4* p4 = (float4*)(partial + ((size_t)b * NCHUNK + chunk) * HID + lane * 8);
    p4[0] = make_float4(a[0], a[1], a[2], a[3]);
    p4[1] = make_float4(a[4], a[5], a[6], a[7]);
    if (tid == 0)
      atomicAdd(&denom[b], wpart[0] + wpart[1] + wpart[2] + wpart[3]);
  }
}

__global__ __launch_bounds__(256) void k_fused(
    const void* ef, const void* eo, const void* maskp, const void* tssp,
    const void* vp, const float* dec, float* w_buf, float* denom,
    float* partial, void* out) {
  if (probe_bf16(tssp))
    k_fused_body<1>(ef, eo, maskp, tssp, vp, dec, w_buf, denom, partial, out);
  else
    k_fused_body<0>(ef, eo, maskp, tssp, vp, dec, w_buf, denom, partial, out);
}

// ---------- K3: finalize att and ctx (needs final denom) ----------
template <int BF>
__device__ __forceinline__ void k_fin_body(
    const float* w_buf, const float* denom, const float* partial, void* out) {
  int b = blockIdx.x;       // 16 blocks
  int tid = threadIdx.x;
  float inv_d = __builtin_amdgcn_rcpf(denom[b]);
  #pragma unroll
  for (int k = 0; k < SEQ / 256; ++k) {
    int s = k * 256 + tid;
    st1<BF>(out, ATT_OFF + b * SEQ + s, w_buf[b * SEQ + s] * inv_d);
  }
  #pragma unroll
  for (int r = 0; r < HID / 256; ++r) {
    int h = r * 256 + tid;
    float sum = 0.0f;
    for (int c = 0; c < NCHUNK; ++c)
      sum += partial[((size_t)b * NCHUNK + c) * HID + h];
    st1<BF>(out, b * HID + h, sum * inv_d);
  }
}

__global__ __launch_bounds__(256) void k_finalize(
    const float* w_buf, const float* denom, const float* partial,
    const void* tssp, void* out) {
  if (probe_bf16(tssp)) k_fin_body<1>(w_buf, denom, partial, out);
  else                  k_fin_body<0>(w_buf, denom, partial, out);
}

extern "C" void kernel_launch(void* const* d_in, const int* in_sizes, int n_in,
                              void* d_out, int out_size, void* d_ws, size_t ws_size,
                              hipStream_t stream) {
  const void* oh   = d_in[0];
  const void* eo   = d_in[1];
  const void* ef   = d_in[2];
  const void* mask = d_in[3];
  const void* tss  = d_in[4];
  const void* W    = d_in[5];
  const void* bias = d_in[6];
  const void* v    = d_in[7];

  float* ws      = (float*)d_ws;
  float* dec     = ws;                    // 8192
  float* w_buf   = dec + BATCH * HID;     // 65536
  float* denom   = w_buf + BATCH * SEQ;   // 16
  float* partial = denom + 16;            // 16*64*512 = 524288 (~2.4 MB total)

  k_dec     <<<2048, 256, 0, stream>>>(oh, W, bias, tss, dec, denom);
  k_fused   <<<1024, 256, 0, stream>>>(ef, eo, mask, tss, v, dec, w_buf,
                                       denom, partial, d_out);
  k_finalize<<<  16, 256, 0, stream>>>(w_buf, denom, partial, tss, d_out);
}

// Round 4
// 301.943 us; speedup vs baseline: 1.0674x; 1.0208x over previous
//
#include <hip/hip_runtime.h>
#include <hip/hip_bf16.h>
#include <stdint.h>

#define SEQ 4096
#define BATCH 16
#define HID 512
#define ATT_OFF (BATCH * HID)                 // 8192  elements into d_out
#define NSS_OFF (BATCH * HID + BATCH * SEQ)   // 73728 elements into d_out
#define SPB 32                                // s per block in fused kernel
#define NCHUNK (SEQ / SPB)                    // 128 chunks per batch
#define SPW (SPB / 4)                         // 8 s per wave

typedef unsigned short u16;
typedef unsigned int u32;

__device__ __forceinline__ float bflo(u32 w) { return __uint_as_float(w << 16); }
__device__ __forceinline__ float bfhi(u32 w) { return __uint_as_float(w & 0xffff0000u); }

__device__ __forceinline__ u16 f2bf(float f) {  // round-to-nearest-even
  u32 u = __float_as_uint(f);
  return (u16)((u + 0x7fffu + ((u >> 16) & 1u)) >> 16);
}

// Runtime dtype probe (insurance; R1-NaN vs R2-pass proved fp32).
__device__ __forceinline__ int probe_bf16(const void* tssp) {
  const u16* t = (const u16*)tssp;
  int ok = 1;
  #pragma unroll
  for (int i = 0; i < 8; i += 2) {
    u16 u = t[i];
    ok &= (u >= 0x3F00 && u <= 0x3FC0) ? 1 : 0;
  }
  return ok;
}

template <int BF>
__device__ __forceinline__ float ld1(const void* p, size_t i) {
  if (BF) return __uint_as_float(((u32)((const u16*)p)[i]) << 16);
  return ((const float*)p)[i];
}

template <int BF>
__device__ __forceinline__ void st1(void* p, size_t i, float v) {
  if (BF) ((u16*)p)[i] = f2bf(v);
  else    ((float*)p)[i] = v;
}

template <int BF>
__device__ __forceinline__ void load8(const void* p, size_t e, float* o) {
  if (BF) {
    uint4 v = *(const uint4*)((const u16*)p + e);
    o[0]=bflo(v.x); o[1]=bfhi(v.x); o[2]=bflo(v.y); o[3]=bfhi(v.y);
    o[4]=bflo(v.z); o[5]=bfhi(v.z); o[6]=bflo(v.w); o[7]=bfhi(v.w);
  } else {
    const float4* f = (const float4*)((const float*)p + e);
    float4 a = f[0], b = f[1];
    o[0]=a.x; o[1]=a.y; o[2]=a.z; o[3]=a.w;
    o[4]=b.x; o[5]=b.y; o[6]=b.z; o[7]=b.w;
  }
}

__device__ __forceinline__ float fast_tanh(float x) {
  float e = __expf(2.0f * x);
  return 1.0f - 2.0f * __builtin_amdgcn_rcpf(e + 1.0f);
}

// ---------- K1: dec[b,k] = sum_h oh[b,h]*W[k,h] + bias[k] ----------
template <int BF>
__device__ __forceinline__ void k_dec_body(
    const void* oh, const void* W, const void* bias, float* dec) {
  int tid = threadIdx.x;
  int gw = blockIdx.x * 4 + (tid >> 6);   // 8192 waves = 16 b * 512 k
  int lane = tid & 63;
  int k = gw & (HID - 1);
  int b = gw >> 9;
  float wv[8], ov[8];
  load8<BF>(W,  (size_t)k * HID + lane * 8, wv);
  load8<BF>(oh, (size_t)b * HID + lane * 8, ov);
  float acc = 0.0f;
  #pragma unroll
  for (int j = 0; j < 8; ++j) acc += wv[j] * ov[j];
  #pragma unroll
  for (int off = 32; off; off >>= 1) acc += __shfl_xor(acc, off, 64);
  if (lane == 0) dec[b * HID + k] = acc + ld1<BF>(bias, k);
}

__global__ __launch_bounds__(256) void k_dec(
    const void* oh, const void* W, const void* bias, const void* tss,
    float* dec, float* denom) {
  if (blockIdx.x == 0 && threadIdx.x < BATCH) denom[threadIdx.x] = 0.0f;
  if (probe_bf16(tss)) k_dec_body<1>(oh, W, bias, dec);
  else                 k_dec_body<0>(oh, W, bias, dec);
}

// ---------- K2: fused scores + context-partial ----------
// 2048 blocks = 16 b * 128 chunks of 32 s; each wave owns 8 consecutive s.
// Phase A: independent per-lane partials acc[i] over ef (MLP-friendly).
// Phase B: BATCHED butterfly -- 6 stages x 8 independent swizzles, so the
//          cross-lane latency is amortized 8x instead of in the per-s chain.
// Phase C: per-s scalars (exp/tss/mask), computed redundantly in all lanes.
// Phase D: stream eo, a[] += w[i]*eo (independent loads).
template <int BF>
__device__ __forceinline__ void k_fused_body(
    const void* ef, const void* eo, const void* maskp, const void* tssp,
    const void* vp, const float* dec, float* w_buf, float* denom,
    float* partial, void* out) {
  int tid = threadIdx.x, lane = tid & 63, wave = tid >> 6;
  int blk = blockIdx.x;
  int b = blk >> 7;                  // 16 b
  int chunk = blk & (NCHUNK - 1);    // 128 chunks
  int s0 = chunk * SPB + wave * SPW;
  float dv[8], vv[8];
  #pragma unroll
  for (int j = 0; j < 8; ++j) dv[j] = dec[b * HID + lane * 8 + j];
  load8<BF>(vp, lane * 8, vv);

  // Phase A
  float acc[SPW];
  #pragma unroll
  for (int i = 0; i < SPW; ++i) {
    float ev[8];
    load8<BF>(ef, ((size_t)(s0 + i) * BATCH + b) * HID + lane * 8, ev);
    float s = 0.0f;
    #pragma unroll
    for (int j = 0; j < 8; ++j) s += fast_tanh(ev[j] + dv[j]) * vv[j];
    acc[i] = s;
  }
  // Phase B: batched butterfly (full sums land in ALL lanes)
  #pragma unroll
  for (int off = 32; off; off >>= 1) {
    #pragma unroll
    for (int i = 0; i < SPW; ++i) acc[i] += __shfl_xor(acc[i], off, 64);
  }
  // Phase C: all lanes compute all w[i] redundantly (uniform loads broadcast)
  float w[SPW];
  float wsum = 0.0f;
  #pragma unroll
  for (int i = 0; i < SPW; ++i) {
    int s = s0 + i;
    float p  = __expf(acc[i]);
    float ts = ld1<BF>(tssp,  b * SEQ + s);
    float m  = ld1<BF>(maskp, b * SEQ + s);
    w[i] = p * m * __builtin_amdgcn_rcpf(ts);
    wsum += w[i];
    if (lane == 0) {
      st1<BF>(out, NSS_OFF + b * SEQ + s, p + ts);
      w_buf[b * SEQ + s] = w[i];
    }
  }
  // Phase D
  float a[8] = {0,0,0,0,0,0,0,0};
  #pragma unroll
  for (int i = 0; i < SPW; ++i) {
    float eov[8];
    load8<BF>(eo, ((size_t)(s0 + i) * BATCH + b) * HID + lane * 8, eov);
    #pragma unroll
    for (int j = 0; j < 8; ++j) a[j] += w[i] * eov[j];
  }
  // Cross-wave reduce; lane-consecutive LDS layout -> conflict-free.
  __shared__ float red[3 * 8 * 64];
  __shared__ float wpart[4];
  if (lane == 0) wpart[wave] = wsum;
  if (wave > 0) {
    #pragma unroll
    for (int j = 0; j < 8; ++j) red[((wave - 1) * 8 + j) * 64 + lane] = a[j];
  }
  __syncthreads();
  if (wave == 0) {
    #pragma unroll
    for (int k = 0; k < 3; ++k)
      #pragma unroll
      for (int j = 0; j < 8; ++j) a[j] += red[(k * 8 + j) * 64 + lane];
    float4* p4 = (float4*)(partial + ((size_t)b * NCHUNK + chunk) * HID + lane * 8);
    p4[0] = make_float4(a[0], a[1], a[2], a[3]);
    p4[1] = make_float4(a[4], a[5], a[6], a[7]);
    if (tid == 0)
      atomicAdd(&denom[b], wpart[0] + wpart[1] + wpart[2] + wpart[3]);
  }
}

__global__ __launch_bounds__(256) void k_fused(
    const void* ef, const void* eo, const void* maskp, const void* tssp,
    const void* vp, const float* dec, float* w_buf, float* denom,
    float* partial, void* out) {
  if (probe_bf16(tssp))
    k_fused_body<1>(ef, eo, maskp, tssp, vp, dec, w_buf, denom, partial, out);
  else
    k_fused_body<0>(ef, eo, maskp, tssp, vp, dec, w_buf, denom, partial, out);
}

// ---------- K3: finalize att and ctx ----------
// 128 blocks = 16 b * 8 parts. Each part: 512 s of att + 64 h of ctx.
template <int BF>
__device__ __forceinline__ void k_fin_body(
    const float* w_buf, const float* denom, const float* partial, void* out) {
  int b = blockIdx.x >> 3;
  int part = blockIdx.x & 7;
  int tid = threadIdx.x;
  float inv_d = __builtin_amdgcn_rcpf(denom[b]);
  #pragma unroll
  for (int k = 0; k < 2; ++k) {
    int s = part * 512 + k * 256 + tid;
    st1<BF>(out, ATT_OFF + b * SEQ + s, w_buf[b * SEQ + s] * inv_d);
  }
  if (tid < 64) {
    int h = part * 64 + tid;
    float sum = 0.0f;
    for (int c = 0; c < NCHUNK; ++c)
      sum += partial[((size_t)b * NCHUNK + c) * HID + h];
    st1<BF>(out, b * HID + h, sum * inv_d);
  }
}

__global__ __launch_bounds__(256) void k_finalize(
    const float* w_buf, const float* denom, const float* partial,
    const void* tssp, void* out) {
  if (probe_bf16(tssp)) k_fin_body<1>(w_buf, denom, partial, out);
  else                  k_fin_body<0>(w_buf, denom, partial, out);
}

extern "C" void kernel_launch(void* const* d_in, const int* in_sizes, int n_in,
                              void* d_out, int out_size, void* d_ws, size_t ws_size,
                              hipStream_t stream) {
  const void* oh   = d_in[0];
  const void* eo   = d_in[1];
  const void* ef   = d_in[2];
  const void* mask = d_in[3];
  const void* tss  = d_in[4];
  const void* W    = d_in[5];
  const void* bias = d_in[6];
  const void* v    = d_in[7];

  float* ws      = (float*)d_ws;
  float* dec     = ws;                    // 8192
  float* w_buf   = dec + BATCH * HID;     // 65536
  float* denom   = w_buf + BATCH * SEQ;   // 16
  float* partial = denom + 16;            // 16*128*512 = 1048576 (~4.5 MB total)

  k_dec     <<<2048, 256, 0, stream>>>(oh, W, bias, tss, dec, denom);
  k_fused   <<<2048, 256, 0, stream>>>(ef, eo, mask, tss, v, dec, w_buf,
                                       denom, partial, d_out);
  k_finalize<<< 128, 256, 0, stream>>>(w_buf, denom, partial, tss, d_out);
}